// Round 4
// baseline (759.072 us; speedup 1.0000x reference)
//
#include <hip/hip_runtime.h>
#include <hip/hip_bf16.h>

#define DD 512
#define BM 32
#define THREADS 512

typedef __attribute__((ext_vector_type(8))) short short8;   // 8 bf16 = 4 VGPRs (MFMA A/B frag)
typedef __attribute__((ext_vector_type(4))) float f32x4;    // MFMA C/D frag

__device__ __forceinline__ unsigned short f2bf(float f) {
  union { float f; unsigned u; } v; v.f = f;
  unsigned r = v.u + 0x7FFFu + ((v.u >> 16) & 1u);  // RNE
  return (unsigned short)(r >> 16);
}
__device__ __forceinline__ float bf2f(unsigned u16) {
  union { unsigned u; float f; } v; v.u = u16 << 16;
  return v.f;
}

// Pack kernel (K x N fp32, row-major) into MFMA-fragment-major bf16:
//   Bpack[((nb*16 + kt)*64 + lane)*8 + j]  holds  B[k][n]
//   with n = nb*16 + (lane&15), k = kt*32 + (lane>>4)*8 + j.
__global__ void prep_bpack(const float* __restrict__ W, unsigned short* __restrict__ Bpack) {
  const int tid = blockIdx.x * blockDim.x + threadIdx.x;   // 262144 threads
  const int n = tid & 511, k = tid >> 9;
  const float w = W[(size_t)k * DD + n];                   // coalesced read
  const int nb = n >> 4, lo = n & 15;
  const int kt = k >> 5, hi = (k >> 3) & 3, j = k & 7;
  const int lane = hi * 16 + lo;
  Bpack[(((size_t)(nb * 16 + kt)) * 64 + lane) * 8 + j] = f2bf(w);
}

// Fused: LN -> relu -> bf16 -> GEMM(Bpack) -> +x +bias.
// Block = 32 rows x 512 cols, 8 waves each own a 32x64 col-strip.
// x is loaded ONCE, directly in MFMA C/D layout, kept in 16 packed-bf16 VGPRs.
__global__ __launch_bounds__(THREADS, 6)   // 3 blocks/CU, VGPR cap ~85
void fused_ln_gemm(const float* __restrict__ x, const float* __restrict__ lns,
                   const float* __restrict__ lnb, const unsigned short* __restrict__ Bpack,
                   const float* __restrict__ bias, float* __restrict__ out) {
  __shared__ unsigned short Alds[BM * 512];   // 32 KB, XOR-swizzled rows
  __shared__ float s_lds[BM][8];              // per-(row, wave) partial sums
  __shared__ float q_lds[BM][8];              // per-(row, wave) partial sumsq

  const int t = threadIdx.x;
  const int lane = t & 63, lo = lane & 15, hi = lane >> 4;
  const int wn = t >> 6;                      // wave's 64-col strip
  const long row0 = (long)blockIdx.x * BM;

  // ---- phase 1: load x tile in C/D layout, fp32 partial row sums -------
  // row(m,q) = m*16 + hi*4 + q ; col(nt) = wn*64 + nt*16 + lo
  float ps[8], pq[8];                 // [m*4+q]
  unsigned xpk[16];                   // [(m*4+nt)*2 + q/2] : bf16(q), bf16(q+1)
  {
    unsigned short tmp[4];            // bf16 of even-q values, per nt
    #pragma unroll
    for (int m = 0; m < 2; ++m) {
      #pragma unroll
      for (int q = 0; q < 4; ++q) {
        const float* xr = x + (row0 + m * 16 + hi * 4 + q) * DD + wn * 64 + lo;
        const float v0 = xr[0], v1 = xr[16], v2 = xr[32], v3 = xr[48];
        ps[m * 4 + q] = (v0 + v1) + (v2 + v3);
        pq[m * 4 + q] = v0 * v0 + v1 * v1 + v2 * v2 + v3 * v3;
        const unsigned short b0 = f2bf(v0), b1 = f2bf(v1), b2 = f2bf(v2), b3 = f2bf(v3);
        if ((q & 1) == 0) {
          tmp[0] = b0; tmp[1] = b1; tmp[2] = b2; tmp[3] = b3;
        } else {
          xpk[(m * 4 + 0) * 2 + (q >> 1)] = (unsigned)tmp[0] | ((unsigned)b0 << 16);
          xpk[(m * 4 + 1) * 2 + (q >> 1)] = (unsigned)tmp[1] | ((unsigned)b1 << 16);
          xpk[(m * 4 + 2) * 2 + (q >> 1)] = (unsigned)tmp[2] | ((unsigned)b2 << 16);
          xpk[(m * 4 + 3) * 2 + (q >> 1)] = (unsigned)tmp[3] | ((unsigned)b3 << 16);
        }
      }
    }
  }
  // reduce across the 16 lo-lanes (stays within hi-group)
  #pragma unroll
  for (int i = 0; i < 8; ++i) {
    #pragma unroll
    for (int msk = 1; msk < 16; msk <<= 1) {
      ps[i] += __shfl_xor(ps[i], msk, 64);
      pq[i] += __shfl_xor(pq[i], msk, 64);
    }
  }
  if (lo == 0) {
    #pragma unroll
    for (int m = 0; m < 2; ++m)
      #pragma unroll
      for (int q = 0; q < 4; ++q) {
        const int r = m * 16 + hi * 4 + q;
        s_lds[r][wn] = ps[m * 4 + q];
        q_lds[r][wn] = pq[m * 4 + q];
      }
  }
  __syncthreads();

  // ---- phase 2: finalize stats, compute h, write swizzled Alds ---------
  {
    float mu[8], rs[8];
    #pragma unroll
    for (int m = 0; m < 2; ++m)
      #pragma unroll
      for (int q = 0; q < 4; ++q) {
        const int r = m * 16 + hi * 4 + q, i = m * 4 + q;
        const float4 a = *(const float4*)&s_lds[r][0];
        const float4 b = *(const float4*)&s_lds[r][4];
        const float4 c = *(const float4*)&q_lds[r][0];
        const float4 d = *(const float4*)&q_lds[r][4];
        const float s  = ((a.x + a.y) + (a.z + a.w)) + ((b.x + b.y) + (b.z + b.w));
        const float s2 = ((c.x + c.y) + (c.z + c.w)) + ((d.x + d.y) + (d.z + d.w));
        mu[i] = s * (1.f / 512.f);
        const float var = fmaxf(s2 * (1.f / 512.f) - mu[i] * mu[i], 0.f);
        rs[i] = rsqrtf(var + 1e-6f);
      }
    #pragma unroll
    for (int nt = 0; nt < 4; ++nt) {
      const int col = wn * 64 + nt * 16 + lo;
      const float sc = lns[col], bi = lnb[col];
      #pragma unroll
      for (int m = 0; m < 2; ++m)
        #pragma unroll
        for (int qq = 0; qq < 2; ++qq) {
          const unsigned p = xpk[(m * 4 + nt) * 2 + qq];
          const int i0 = m * 4 + qq * 2;
          const unsigned short h0 = f2bf(fmaxf((bf2f(p & 0xffffu) - mu[i0]) * rs[i0] * sc + bi, 0.f));
          const unsigned short h1 = f2bf(fmaxf((bf2f(p >> 16) - mu[i0 + 1]) * rs[i0 + 1] * sc + bi, 0.f));
          const int r0 = m * 16 + hi * 4 + qq * 2;
          const unsigned a0 = (unsigned)(r0 * 1024 + col * 2) ^ (unsigned)((r0 & 7) << 4);
          const unsigned a1 = (unsigned)((r0 + 1) * 1024 + col * 2) ^ (unsigned)(((r0 + 1) & 7) << 4);
          *(unsigned short*)((char*)Alds + a0) = h0;
          *(unsigned short*)((char*)Alds + a1) = h1;
        }
    }
  }
  __syncthreads();

  // ---- phase 3: GEMM (no barriers in K-loop) ----------------------------
  unsigned abase0, aswz0, abase1, aswz1;
  {
    const int r0 = lo;       abase0 = (unsigned)(r0 * 1024 + hi * 16); aswz0 = (unsigned)((r0 & 7) << 4);
    const int r1 = 16 + lo;  abase1 = (unsigned)(r1 * 1024 + hi * 16); aswz1 = (unsigned)((r1 & 7) << 4);
  }
  const short8* bbase = (const short8*)Bpack + (size_t)wn * 4096 + lane;

  f32x4 acc00 = {}, acc01 = {}, acc02 = {}, acc03 = {};
  f32x4 acc10 = {}, acc11 = {}, acc12 = {}, acc13 = {};

  #pragma unroll
  for (int kt = 0; kt < 16; ++kt) {
    const short8 b0 = bbase[(0 * 16 + kt) * 64];
    const short8 b1 = bbase[(1 * 16 + kt) * 64];
    const short8 b2 = bbase[(2 * 16 + kt) * 64];
    const short8 b3 = bbase[(3 * 16 + kt) * 64];
    const short8 a0 = *(const short8*)((const char*)Alds + ((abase0 + (unsigned)kt * 64) ^ aswz0));
    const short8 a1 = *(const short8*)((const char*)Alds + ((abase1 + (unsigned)kt * 64) ^ aswz1));
    acc00 = __builtin_amdgcn_mfma_f32_16x16x32_bf16(a0, b0, acc00, 0, 0, 0);
    acc10 = __builtin_amdgcn_mfma_f32_16x16x32_bf16(a1, b0, acc10, 0, 0, 0);
    acc01 = __builtin_amdgcn_mfma_f32_16x16x32_bf16(a0, b1, acc01, 0, 0, 0);
    acc11 = __builtin_amdgcn_mfma_f32_16x16x32_bf16(a1, b1, acc11, 0, 0, 0);
    acc02 = __builtin_amdgcn_mfma_f32_16x16x32_bf16(a0, b2, acc02, 0, 0, 0);
    acc12 = __builtin_amdgcn_mfma_f32_16x16x32_bf16(a1, b2, acc12, 0, 0, 0);
    acc03 = __builtin_amdgcn_mfma_f32_16x16x32_bf16(a0, b3, acc03, 0, 0, 0);
    acc13 = __builtin_amdgcn_mfma_f32_16x16x32_bf16(a1, b3, acc13, 0, 0, 0);
  }

  // ---- epilogue: out = x + acc + bias (x from xpk registers) -----------
  {
    const f32x4 accs[2][4] = {{acc00, acc01, acc02, acc03}, {acc10, acc11, acc12, acc13}};
    #pragma unroll
    for (int nt = 0; nt < 4; ++nt) {
      const int col = wn * 64 + nt * 16 + lo;
      const float bv = bias[col];
      #pragma unroll
      for (int m = 0; m < 2; ++m)
        #pragma unroll
        for (int q = 0; q < 4; ++q) {
          const unsigned p = xpk[(m * 4 + nt) * 2 + (q >> 1)];
          const float xv = bf2f((q & 1) ? (p >> 16) : (p & 0xffffu));
          out[(row0 + m * 16 + hi * 4 + q) * DD + col] = accs[m][nt][q] + xv + bv;
        }
    }
  }
}

extern "C" void kernel_launch(void* const* d_in, const int* in_sizes, int n_in,
                              void* d_out, int out_size, void* d_ws, size_t ws_size,
                              hipStream_t stream) {
  const float* x    = (const float*)d_in[0];
  const float* lns  = (const float*)d_in[1];
  const float* lnb  = (const float*)d_in[2];
  const float* W    = (const float*)d_in[3];
  const float* bias = (const float*)d_in[4];
  float* out = (float*)d_out;
  unsigned short* Bpack = (unsigned short*)d_ws;   // 512KB scratch

  const int nrows = in_sizes[0] / DD;

  prep_bpack<<<DD * DD / 256, 256, 0, stream>>>(W, Bpack);
  fused_ln_gemm<<<nrows / BM, THREADS, 0, stream>>>(x, lns, lnb, Bpack, bias, out);
}

// Round 5
// 362.870 us; speedup vs baseline: 2.0919x; 2.0919x over previous
//
#include <hip/hip_runtime.h>
#include <hip/hip_bf16.h>

#define DD 512
#define BM 32
#define THREADS 512

typedef __attribute__((ext_vector_type(8))) short short8;   // 8 bf16 = 4 VGPRs (MFMA A/B frag)
typedef __attribute__((ext_vector_type(4))) float f32x4;    // MFMA C/D frag

__device__ __forceinline__ unsigned short f2bf(float f) {
  union { float f; unsigned u; } v; v.f = f;
  unsigned r = v.u + 0x7FFFu + ((v.u >> 16) & 1u);  // RNE
  return (unsigned short)(r >> 16);
}

// Pack kernel (K x N fp32, row-major) into MFMA-fragment-major bf16:
//   Bpack[((nb*16 + kt)*64 + lane)*8 + j]  holds  B[k][n]
//   with n = nb*16 + (lane&15), k = kt*32 + (lane>>4)*8 + j.
__global__ void prep_bpack(const float* __restrict__ W, unsigned short* __restrict__ Bpack) {
  const int tid = blockIdx.x * blockDim.x + threadIdx.x;   // 262144 threads
  const int n = tid & 511, k = tid >> 9;
  const float w = W[(size_t)k * DD + n];                   // coalesced read
  const int nb = n >> 4, lo = n & 15;
  const int kt = k >> 5, hi = (k >> 3) & 3, j = k & 7;
  const int lane = hi * 16 + lo;
  Bpack[(((size_t)(nb * 16 + kt)) * 64 + lane) * 8 + j] = f2bf(w);
}

// Fused: LN -> relu -> bf16 -> GEMM(Bpack) -> +x +bias.
// Block = 32 rows x 512 cols, 8 waves each own a 32x64 col-strip.
// Residual: acc is INITIALIZED with x + bias (x re-read in C/D layout, L2-hot),
// so no Xlds buffer and no per-thread x register array.
__global__ __launch_bounds__(THREADS, 6)   // target 3 blocks/CU
void fused_ln_gemm(const float* __restrict__ x, const float* __restrict__ lns,
                   const float* __restrict__ lnb, const unsigned short* __restrict__ Bpack,
                   const float* __restrict__ bias, float* __restrict__ out) {
  __shared__ unsigned short Alds[BM * 512];   // 32 KB, XOR-swizzled rows

  const int t = threadIdx.x;
  const long row0 = (long)blockIdx.x * BM;

  // ---------------- phase 1: LN + relu, 16 threads per row --------------
  {
    const int r = t >> 4, g = t & 15;
    const float* xr = x + (row0 + r) * DD + g * 4;
    float4 v[8];
    float s = 0.f, s2 = 0.f;
    #pragma unroll
    for (int i = 0; i < 8; ++i) {
      v[i] = *(const float4*)(xr + i * 64);
      s  += (v[i].x + v[i].y) + (v[i].z + v[i].w);
      s2 += v[i].x * v[i].x + v[i].y * v[i].y + v[i].z * v[i].z + v[i].w * v[i].w;
    }
    #pragma unroll
    for (int m = 1; m < 16; m <<= 1) {   // 16-lane group reduce (within wave)
      s  += __shfl_xor(s,  m, 64);
      s2 += __shfl_xor(s2, m, 64);
    }
    const float mu   = s * (1.f / 512.f);
    const float var  = fmaxf(s2 * (1.f / 512.f) - mu * mu, 0.f);
    const float rstd = rsqrtf(var + 1e-6f);
    #pragma unroll
    for (int i = 0; i < 8; ++i) {
      const int c = g * 4 + i * 64;
      const float4 sc = *(const float4*)(lns + c);
      const float4 bi = *(const float4*)(lnb + c);
      ushort4 hu;
      hu.x = f2bf(fmaxf((v[i].x - mu) * rstd * sc.x + bi.x, 0.f));
      hu.y = f2bf(fmaxf((v[i].y - mu) * rstd * sc.y + bi.y, 0.f));
      hu.z = f2bf(fmaxf((v[i].z - mu) * rstd * sc.z + bi.z, 0.f));
      hu.w = f2bf(fmaxf((v[i].w - mu) * rstd * sc.w + bi.w, 0.f));
      // byte addr (r*1024 + c*2) ^ ((r&7)<<4) — 8B-aligned stays 8B-aligned
      const unsigned a = (unsigned)(r * 1024 + g * 8 + i * 128) ^ (unsigned)((r & 7) << 4);
      *(ushort4*)((char*)Alds + a) = hu;
    }
  }
  __syncthreads();

  // ---------------- phase 2: acc = x + bias (C/D layout, L2-hot) --------
  const int lane = t & 63, lo = lane & 15, hi = lane >> 4;
  const int wn = t >> 6;                       // wave's 64-col strip

  const float* xc = x + (row0 + hi * 4) * DD + wn * 64 + lo;   // row (m*16+hi*4+q), col +nt*16
  const float bv0 = bias[wn * 64 +  0 + lo];
  const float bv1 = bias[wn * 64 + 16 + lo];
  const float bv2 = bias[wn * 64 + 32 + lo];
  const float bv3 = bias[wn * 64 + 48 + lo];

  f32x4 acc00, acc01, acc02, acc03, acc10, acc11, acc12, acc13;
  #pragma unroll
  for (int q = 0; q < 4; ++q) {
    const float* r0 = xc + q * DD;            // m = 0
    const float* r1 = xc + (16 * DD) + q * DD; // m = 1
    acc00[q] = r0[ 0] + bv0;  acc01[q] = r0[16] + bv1;
    acc02[q] = r0[32] + bv2;  acc03[q] = r0[48] + bv3;
    acc10[q] = r1[ 0] + bv0;  acc11[q] = r1[16] + bv1;
    acc12[q] = r1[32] + bv2;  acc13[q] = r1[48] + bv3;
  }

  // ---------------- phase 3: GEMM (no barriers in K-loop) ---------------
  unsigned abase0, aswz0, abase1, aswz1;
  {
    const int r0 = lo;       abase0 = (unsigned)(r0 * 1024 + hi * 16); aswz0 = (unsigned)((r0 & 7) << 4);
    const int r1 = 16 + lo;  abase1 = (unsigned)(r1 * 1024 + hi * 16); aswz1 = (unsigned)((r1 & 7) << 4);
  }
  const short8* bbase = (const short8*)Bpack + (size_t)wn * 4096 + lane;

  #pragma unroll
  for (int kt = 0; kt < 16; ++kt) {
    const short8 b0 = bbase[(0 * 16 + kt) * 64];
    const short8 b1 = bbase[(1 * 16 + kt) * 64];
    const short8 b2 = bbase[(2 * 16 + kt) * 64];
    const short8 b3 = bbase[(3 * 16 + kt) * 64];
    const short8 a0 = *(const short8*)((const char*)Alds + ((abase0 + (unsigned)kt * 64) ^ aswz0));
    const short8 a1 = *(const short8*)((const char*)Alds + ((abase1 + (unsigned)kt * 64) ^ aswz1));
    acc00 = __builtin_amdgcn_mfma_f32_16x16x32_bf16(a0, b0, acc00, 0, 0, 0);
    acc10 = __builtin_amdgcn_mfma_f32_16x16x32_bf16(a1, b0, acc10, 0, 0, 0);
    acc01 = __builtin_amdgcn_mfma_f32_16x16x32_bf16(a0, b1, acc01, 0, 0, 0);
    acc11 = __builtin_amdgcn_mfma_f32_16x16x32_bf16(a1, b1, acc11, 0, 0, 0);
    acc02 = __builtin_amdgcn_mfma_f32_16x16x32_bf16(a0, b2, acc02, 0, 0, 0);
    acc12 = __builtin_amdgcn_mfma_f32_16x16x32_bf16(a1, b2, acc12, 0, 0, 0);
    acc03 = __builtin_amdgcn_mfma_f32_16x16x32_bf16(a0, b3, acc03, 0, 0, 0);
    acc13 = __builtin_amdgcn_mfma_f32_16x16x32_bf16(a1, b3, acc13, 0, 0, 0);
  }

  // ---------------- epilogue: pure store --------------------------------
  float* oc = out + (row0 + hi * 4) * DD + wn * 64 + lo;
  #pragma unroll
  for (int q = 0; q < 4; ++q) {
    float* r0 = oc + q * DD;
    float* r1 = oc + (16 * DD) + q * DD;
    r0[ 0] = acc00[q];  r0[16] = acc01[q];  r0[32] = acc02[q];  r0[48] = acc03[q];
    r1[ 0] = acc10[q];  r1[16] = acc11[q];  r1[32] = acc12[q];  r1[48] = acc13[q];
  }
}

extern "C" void kernel_launch(void* const* d_in, const int* in_sizes, int n_in,
                              void* d_out, int out_size, void* d_ws, size_t ws_size,
                              hipStream_t stream) {
  const float* x    = (const float*)d_in[0];
  const float* lns  = (const float*)d_in[1];
  const float* lnb  = (const float*)d_in[2];
  const float* W    = (const float*)d_in[3];
  const float* bias = (const float*)d_in[4];
  float* out = (float*)d_out;
  unsigned short* Bpack = (unsigned short*)d_ws;   // 512KB scratch

  const int nrows = in_sizes[0] / DD;

  prep_bpack<<<DD * DD / 256, 256, 0, stream>>>(W, Bpack);
  fused_ln_gemm<<<nrows / BM, THREADS, 0, stream>>>(x, lns, lnb, Bpack, bias, out);
}